// Round 2
// baseline (398.450 us; speedup 1.0000x reference)
//
#include <hip/hip_runtime.h>

// RegressionWisard predict (centrality='mean')
//   input:  [B=4096, E=8192] int32 bits
//   map:    [E] permutation int32 (identity in the benchmark)
//   counts: [N=512, 65536] int32
//   sums:   [N=512, 65536] float32
//   out:    [B] float32 = nan_to_num(sum(s where c>0) / sum(c where c>0))
//
// R4: R2/R3 both pin at ~2.4 TB/s with FETCH at the compulsory floor ->
// DRAM-efficiency-bound on the random 64B line stream, not MLP/traffic.
// Transpose: lane = sample, neuron = wave-uniform. Each gather instruction's
// 64 requests then target ONE neuron's 256KB table slice, and all blocks
// sweep neurons in the same order -> device-wide active window ~16MB
// (vs 256MB) -> DRAM row-buffer hits + temporally-adjacent line reuse.
// No atomics: race-free partials [8][4096] in workspace + tiny finalize.

constexpr int BATCH   = 4096;
constexpr int ENTRY   = 8192;
constexpr int TUP     = 16;
constexpr int NEUR    = ENTRY / TUP;    // 512
constexpr int THREADS = 256;
constexpr int NC      = 8;              // neuron chunks (64 neurons each)
constexpr int SC      = BATCH / 64;     // 64 sample chunks (64 samples each)
constexpr int NPT     = 16;             // neurons per thread (wave covers 16)

typedef int v4i __attribute__((ext_vector_type(4)));

__global__ __launch_bounds__(THREADS) void wisard_gather(
    const int*   __restrict__ input,
    const int*   __restrict__ mapping,
    const int*   __restrict__ counts,
    const float* __restrict__ sums,
    float*       __restrict__ part_r,   // [NC][BATCH]
    int*         __restrict__ part_c)   // [NC][BATCH]
{
    __shared__ float sr [4][64];
    __shared__ int   scn[4][64];

    const int tid  = threadIdx.x;
    const int lane = tid & 63;
    const int w    = tid >> 6;
    const int nc   = blockIdx.x & (NC - 1);   // low bits -> one nc per XCD
    const int sc   = blockIdx.x >> 3;
    const int s    = sc * 64 + lane;          // lane = sample
    const int nb   = nc * 64 + w * NPT;       // wave-uniform neuron base

    int   cv[NPT];
    float sv[NPT];

    #pragma unroll
    for (int i = 0; i < NPT; ++i) {
        // neuron index is wave-uniform: force scalar so the mapping
        // contiguity check compiles to s_load + s_cbranch.
        const int n = __builtin_amdgcn_readfirstlane(nb) + i;
        const int* map_n = mapping + n * TUP;

        const int m0 = map_n[0];
        bool contig = ((m0 & 3) == 0);
        #pragma unroll
        for (int t = 1; t < TUP; ++t) contig &= (map_n[t] == m0 + t);

        int addr;
        if (contig) {
            // one 64B input line per (sample, neuron), fully consumed
            const v4i* p = reinterpret_cast<const v4i*>(
                input + (size_t)s * ENTRY + m0);
            const v4i a0 = __builtin_nontemporal_load(p);
            const v4i a1 = __builtin_nontemporal_load(p + 1);
            const v4i a2 = __builtin_nontemporal_load(p + 2);
            const v4i a3 = __builtin_nontemporal_load(p + 3);
            // tuple bit 0 is the MSB of the address
            addr = ((a0.x & 1) << 15) | ((a0.y & 1) << 14)
                 | ((a0.z & 1) << 13) | ((a0.w & 1) << 12)
                 | ((a1.x & 1) << 11) | ((a1.y & 1) << 10)
                 | ((a1.z & 1) <<  9) | ((a1.w & 1) <<  8)
                 | ((a2.x & 1) <<  7) | ((a2.y & 1) <<  6)
                 | ((a2.z & 1) <<  5) | ((a2.w & 1) <<  4)
                 | ((a3.x & 1) <<  3) | ((a3.y & 1) <<  2)
                 | ((a3.z & 1) <<  1) |  (a3.w & 1);
        } else {
            // general permutation: scalar bit gathers (cold path)
            const int* row = input + (size_t)s * ENTRY;
            int a = 0;
            #pragma unroll
            for (int t = 0; t < TUP; ++t) a = (a << 1) | (row[map_n[t]] & 1);
            addr = a;
        }

        // Both gathers for this neuron: 64 lanes -> one 256KB table slice.
        // Results unused until after the loop -> up to 32 loads in flight.
        const size_t idx = ((size_t)n << 16) | (unsigned)addr;
        cv[i] = counts[idx];
        sv[i] = sums  [idx];
    }

    float r = 0.0f; int c = 0;
    #pragma unroll
    for (int i = 0; i < NPT; ++i) {
        const bool t = cv[i] > 0;
        r += t ? sv[i] : 0.0f;
        c += t ? cv[i] : 0;
    }

    // reduce the 4 waves' partials per sample (lane = sample)
    sr[w][lane] = r; scn[w][lane] = c;
    __syncthreads();
    if (w == 0) {
        r = sr[0][lane] + sr[1][lane] + sr[2][lane] + sr[3][lane];
        c = scn[0][lane] + scn[1][lane] + scn[2][lane] + scn[3][lane];
        part_r[nc * BATCH + s] = r;
        part_c[nc * BATCH + s] = c;
    }
}

__global__ __launch_bounds__(THREADS) void wisard_finalize(
    const float* __restrict__ part_r,
    const int*   __restrict__ part_c,
    float*       __restrict__ out)
{
    const int s = blockIdx.x * THREADS + threadIdx.x;
    float r = 0.0f; int c = 0;
    #pragma unroll
    for (int nc = 0; nc < NC; ++nc) {
        r += part_r[nc * BATCH + s];
        c += part_c[nc * BATCH + s];
    }
    out[s] = (c > 0) ? (r / (float)c) : 0.0f;   // nan_to_num(0/0)==0
}

extern "C" void kernel_launch(void* const* d_in, const int* in_sizes, int n_in,
                              void* d_out, int out_size, void* d_ws, size_t ws_size,
                              hipStream_t stream) {
    (void)in_sizes; (void)n_in; (void)out_size; (void)ws_size;
    const int*   input   = (const int*)d_in[0];
    const int*   mapping = (const int*)d_in[1];
    const int*   counts  = (const int*)d_in[2];
    const float* sums    = (const float*)d_in[3];
    float*       out     = (float*)d_out;

    float* part_r = (float*)d_ws;
    int*   part_c = (int*)((char*)d_ws + (size_t)NC * BATCH * sizeof(float));

    wisard_gather<<<SC * NC, THREADS, 0, stream>>>(
        input, mapping, counts, sums, part_r, part_c);
    wisard_finalize<<<BATCH / THREADS, THREADS, 0, stream>>>(part_r, part_c, out);
}